// Round 9
// baseline (14360.191 us; speedup 1.0000x reference)
//
#include <hip/hip_runtime.h>
#include <hip/hip_bf16.h>

// NeuralODE Bosh3 fixed-step integrator, persistent-block formulation.
// Round 9: BT=32, 64 blocks x 512 threads (8 waves). Weight streaming via
// global_load_lds (fire-and-forget DMA) into per-wave 2x4KB LDS ring slots,
// double-buffered at kt granularity with counted s_waitcnt vmcnt(N).
// Each wave owns 4 N-tiles (layers 1/2) + 1 layer-3 tile + ODE state.
// Register pressure ~70 VGPR -> no spill possible. LDS 156KB static.

#define B_ 2048
#define L_ 128
#define P_ 8
#define W_ 512
#define T_ 128
#define BT_ 32
#define NBLK (B_/BT_)          // 64 blocks

#define KT1 5
#define KT2 16
#define KT3 16

typedef __attribute__((ext_vector_type(8))) short short8;
typedef __attribute__((ext_vector_type(4))) float f32x4;

// packed weight sizes (ushort elements); fragment = 64 lanes x 8 = 512
#define W0P_ELEMS (8*KT1*4*512)   // [wv8][kt5][n4]
#define W1P_ELEMS (8*KT2*4*512)   // [wv8][kt16][n4]
#define W2P_ELEMS (8*KT3*512)     // [wv8][kt16]
#define W1P_OFF (W0P_ELEMS)
#define W2P_OFF (W0P_ELEMS + W1P_ELEMS)
#define WTOT (W0P_ELEMS + W1P_ELEMS + W2P_ELEMS)   // 409600 ushorts

#define VMWAIT0 asm volatile("s_waitcnt vmcnt(0)" ::: "memory")
#define VMWAIT1 asm volatile("s_waitcnt vmcnt(1)" ::: "memory")
#define VMWAIT4 asm volatile("s_waitcnt vmcnt(4)" ::: "memory")
#define CFENCE  asm volatile("" ::: "memory")

__device__ __forceinline__ unsigned short f2bf(float f){
  unsigned u = __builtin_bit_cast(unsigned, f);
  u += 0x7fffu + ((u >> 16) & 1u);          // round-to-nearest-even
  return (unsigned short)(u >> 16);
}

__device__ __forceinline__ float tanh_fast(float x){
  float e = __expf(2.0f * x);
  return 1.0f - __fdividef(2.0f, e + 1.0f); // exact at saturation (+-1)
}

// async 16B/lane global->LDS: LDS dest = uniform base + lane*16
__device__ __forceinline__ void gld16(const unsigned short* g, unsigned short* l){
  __builtin_amdgcn_global_load_lds(
      (const __attribute__((address_space(1))) unsigned int*)(const void*)g,
      (__attribute__((address_space(3))) unsigned int*)(void*)l,
      16, 0, 0);
}

// Pack W[n][k] (row-major fp32) into per-wave-contiguous MFMA B-fragments.
// L1/L2: tile = (wv*KT + kt)*4 + n -> nt = 4*wv + n; elem tile*512 + lane*8
//        + j holds bf16(W[nt*16+(lane&15)][kt*32+(lane>>4)*8+j]).
// L3:    tile = wv*16 + kt.
// idx in [WTOT, WTOT+T_-1): dts[idx-WTOT] = ts[i+1]-ts[i] (fp32) at wp+WTOT.
__global__ void prep_weights(const float* __restrict__ W0,
                             const float* __restrict__ W1,
                             const float* __restrict__ W2,
                             const float* __restrict__ ts,
                             unsigned short* __restrict__ wp){
  int idx = blockIdx.x * blockDim.x + threadIdx.x;
  if (idx >= WTOT){
    int t = idx - WTOT;
    if (t < T_ - 1){
      float* dts = (float*)(wp + WTOT);
      dts[t] = ts[t+1] - ts[t];
    }
    return;
  }
  const float* src; int base, KT, Korig, isL3;
  if (idx < W1P_OFF)      { src = W0; base = 0;       KT = KT1; Korig = 136; isL3 = 0; }
  else if (idx < W2P_OFF) { src = W1; base = W1P_OFF; KT = KT2; Korig = 512; isL3 = 0; }
  else                    { src = W2; base = W2P_OFF; KT = KT3; Korig = 512; isL3 = 1; }
  int e    = idx - base;
  int j    = e & 7;
  int lane = (e >> 3) & 63;
  int tile = e >> 9;
  int nt, kt;
  if (isL3){ kt = tile & 15; nt = tile >> 4; }
  else     { int n = tile & 3; int r2 = tile >> 2; kt = r2 % KT; nt = 4*(r2 / KT) + n; }
  int row  = nt*16 + (lane & 15);
  int k    = kt*32 + ((lane >> 4) << 3) + j;
  float v  = (k < Korig) ? src[row*Korig + k] : 0.0f;
  wp[idx] = f2bf(v);
}

// LDS act layouts (bf16, XOR-swizzled: byte ^= (row&7)<<4 within the row).
#define XROWB 384    // x: 192 ushorts/row (0..127 y, 128..135 args, rest 0)
#define HROWB 1024   // h: 512 ushorts/row

__global__ __launch_bounds__(512, 2)
void ode_main(const float* __restrict__ x0,
              const float* __restrict__ args,
              const float* __restrict__ b0, const float* __restrict__ b1,
              const float* __restrict__ b2,
              const unsigned short* __restrict__ wp,
              float* __restrict__ out){
  __shared__ __align__(16) unsigned short xb[BT_*(XROWB/2)];   // 12 KiB
  __shared__ __align__(16) unsigned short h1[BT_*(HROWB/2)];   // 32 KiB
  __shared__ __align__(16) unsigned short h2[BT_*(HROWB/2)];   // 32 KiB
  __shared__ __align__(16) float ybuf[BT_][L_];                // 16 KiB
  __shared__ __align__(16) unsigned short wsl[8*4096];         // 64 KiB ring slots

  const int tid  = threadIdx.x;
  const int lane = tid & 63;
  const int wv   = tid >> 6;     // wave 0..7
  const int lo   = lane & 15;
  const int hi   = lane >> 4;    // 0..3
  const int r0   = blockIdx.x * BT_;

  const unsigned short* w0p = wp;
  const unsigned short* w1p = wp + W1P_OFF;
  const unsigned short* w2p = wp + W2P_OFF;
  const float* dts = (const float*)(wp + WTOT);

  // per-lane weight stream bases
  const unsigned short* w0l = w0p + (size_t)(wv*KT1*4)*512 + lane*8;
  const unsigned short* w1l = w1p + (size_t)(wv*KT2*4)*512 + lane*8;
  const unsigned short* w2l = w2p + (size_t)(wv*KT3  )*512 + lane*8;
  unsigned short* slot0 = wsl + wv*4096;
  unsigned short* slot1 = wsl + wv*4096 + 2048;

  // zero x buffer (zeroes are swizzle-invariant)
  for (int i = tid; i < BT_*(XROWB/2); i += 512) xb[i] = 0;
  __syncthreads();

  // args -> x cols 128..135 (constant across all steps)
  if (tid < BT_*P_){
    int r = tid >> 3, pp = tid & 7;
    unsigned short v = f2bf(args[(r0 + r)*P_ + pp]);
    *(unsigned short*)((char*)xb + r*XROWB + (((128 + pp)*2) ^ ((r & 7) << 4))) = v;
  }

  const int aswz = (lo & 7) << 4;

  // biases: wave owns nt = 4wv+n (layers 1/2), col block wv (layer 3)
  float b0v[4], b1v[4];
  #pragma unroll
  for (int n = 0; n < 4; ++n){
    b0v[n] = b0[(4*wv + n)*16 + lo];
    b1v[n] = b1[(4*wv + n)*16 + lo];
  }
  const int c3 = wv*16 + lo;
  float b2v = b2[c3];

  // ODE state: rows p*16+4hi+j (p=0,1), col c3
  float yr[2][4], yn[2][4];
  #pragma unroll
  for (int p = 0; p < 2; ++p)
    #pragma unroll
    for (int j = 0; j < 4; ++j){
      int row = p*16 + 4*hi + j;
      float v = x0[(r0 + row)*L_ + c3];
      yr[p][j] = v;
      ybuf[row][c3] = v;
      *(unsigned short*)((char*)xb + row*XROWB + ((c3*2) ^ ((row & 7) << 4))) = f2bf(v);
    }

  // One vector-field eval. Weights DMA'd kt-by-kt into ring slots.
  auto evalf = [&](f32x4 (&dout)[2]){
    // ---- layer 1: KT=5, 4 frags/kt
    {
      f32x4 acc[4][2];
      #pragma unroll
      for (int n = 0; n < 4; ++n){ acc[n][0] = f32x4{0,0,0,0}; acc[n][1] = f32x4{0,0,0,0}; }
      #pragma unroll
      for (int n = 0; n < 4; ++n) gld16(w0l + (size_t)(0*4 + n)*512, slot0 + n*512);
      #pragma unroll
      for (int n = 0; n < 4; ++n) gld16(w0l + (size_t)(1*4 + n)*512, slot1 + n*512);
      #pragma unroll
      for (int kt = 0; kt < KT1; ++kt){
        unsigned short* sl = (kt & 1) ? slot1 : slot0;
        if (kt == KT1-1) VMWAIT0; else VMWAIT4;
        short8 wf[4];
        #pragma unroll
        for (int n = 0; n < 4; ++n) wf[n] = *(const short8*)(sl + n*512 + lane*8);
        short8 a0 = *(const short8*)((const char*)xb + lo*XROWB      + ((kt*64 + hi*16) ^ aswz));
        short8 a1 = *(const short8*)((const char*)xb + (16+lo)*XROWB + ((kt*64 + hi*16) ^ aswz));
        CFENCE;
        if (kt + 2 < KT1){
          #pragma unroll
          for (int n = 0; n < 4; ++n) gld16(w0l + (size_t)((kt+2)*4 + n)*512, sl + n*512);
        }
        #pragma unroll
        for (int n = 0; n < 4; ++n){
          acc[n][0] = __builtin_amdgcn_mfma_f32_16x16x32_bf16(a0, wf[n], acc[n][0], 0, 0, 0);
          acc[n][1] = __builtin_amdgcn_mfma_f32_16x16x32_bf16(a1, wf[n], acc[n][1], 0, 0, 0);
        }
      }
      #pragma unroll
      for (int n = 0; n < 4; ++n)
        #pragma unroll
        for (int p = 0; p < 2; ++p)
          #pragma unroll
          for (int j = 0; j < 4; ++j){
            float v = tanh_fast(acc[n][p][j] + b0v[n]);
            int row = p*16 + 4*hi + j;
            int col = (4*wv + n)*16 + lo;
            *(unsigned short*)((char*)h1 + row*HROWB + ((col*2) ^ ((row & 7) << 4))) = f2bf(v);
          }
    }
    __syncthreads();
    // ---- layer 2: KT=16, 4 frags/kt
    {
      f32x4 acc[4][2];
      #pragma unroll
      for (int n = 0; n < 4; ++n){ acc[n][0] = f32x4{0,0,0,0}; acc[n][1] = f32x4{0,0,0,0}; }
      #pragma unroll
      for (int n = 0; n < 4; ++n) gld16(w1l + (size_t)(0*4 + n)*512, slot0 + n*512);
      #pragma unroll
      for (int n = 0; n < 4; ++n) gld16(w1l + (size_t)(1*4 + n)*512, slot1 + n*512);
      #pragma unroll
      for (int kt = 0; kt < KT2; ++kt){
        unsigned short* sl = (kt & 1) ? slot1 : slot0;
        if (kt == KT2-1) VMWAIT0; else VMWAIT4;
        short8 wf[4];
        #pragma unroll
        for (int n = 0; n < 4; ++n) wf[n] = *(const short8*)(sl + n*512 + lane*8);
        short8 a0 = *(const short8*)((const char*)h1 + lo*HROWB      + ((kt*64 + hi*16) ^ aswz));
        short8 a1 = *(const short8*)((const char*)h1 + (16+lo)*HROWB + ((kt*64 + hi*16) ^ aswz));
        CFENCE;
        if (kt + 2 < KT2){
          #pragma unroll
          for (int n = 0; n < 4; ++n) gld16(w1l + (size_t)((kt+2)*4 + n)*512, sl + n*512);
        }
        #pragma unroll
        for (int n = 0; n < 4; ++n){
          acc[n][0] = __builtin_amdgcn_mfma_f32_16x16x32_bf16(a0, wf[n], acc[n][0], 0, 0, 0);
          acc[n][1] = __builtin_amdgcn_mfma_f32_16x16x32_bf16(a1, wf[n], acc[n][1], 0, 0, 0);
        }
      }
      #pragma unroll
      for (int n = 0; n < 4; ++n)
        #pragma unroll
        for (int p = 0; p < 2; ++p)
          #pragma unroll
          for (int j = 0; j < 4; ++j){
            float v = tanh_fast(acc[n][p][j] + b1v[n]);
            int row = p*16 + 4*hi + j;
            int col = (4*wv + n)*16 + lo;
            *(unsigned short*)((char*)h2 + row*HROWB + ((col*2) ^ ((row & 7) << 4))) = f2bf(v);
          }
    }
    __syncthreads();
    // ---- layer 3: KT=16, 1 frag/kt; wave wv owns col block wv, both panels
    {
      f32x4 a3[2];
      a3[0] = f32x4{0,0,0,0};
      a3[1] = f32x4{0,0,0,0};
      gld16(w2l + (size_t)0*512, slot0);
      gld16(w2l + (size_t)1*512, slot1);
      #pragma unroll
      for (int kt = 0; kt < KT3; ++kt){
        unsigned short* sl = (kt & 1) ? slot1 : slot0;
        if (kt == KT3-1) VMWAIT0; else VMWAIT1;
        short8 wf = *(const short8*)(sl + lane*8);
        short8 a0 = *(const short8*)((const char*)h2 + lo*HROWB      + ((kt*64 + hi*16) ^ aswz));
        short8 a1 = *(const short8*)((const char*)h2 + (16+lo)*HROWB + ((kt*64 + hi*16) ^ aswz));
        CFENCE;
        if (kt + 2 < KT3) gld16(w2l + (size_t)(kt+2)*512, sl);
        a3[0] = __builtin_amdgcn_mfma_f32_16x16x32_bf16(a0, wf, a3[0], 0, 0, 0);
        a3[1] = __builtin_amdgcn_mfma_f32_16x16x32_bf16(a1, wf, a3[1], 0, 0, 0);
      }
      dout[0] = a3[0];
      dout[1] = a3[1];
    }
  };

  VMWAIT0;   // drain init loads so counted vmcnt sees only weight DMA
  // Bosh3: k1=f(y); k2=f(y+dt/2 k1); k3=f(y+3dt/4 k2); y+=dt(2/9 k1+1/3 k2+4/9 k3)
  for (int t = 1; t < T_; ++t){
    float dt = dts[t-1];
    f32x4 d[2];

    __syncthreads();                       // xb + ybuf ready
    #pragma unroll
    for (int it = 0; it < 2; ++it){        // store y_{t-1}: 32 rows x 512 B
      int row = (tid >> 5) + it*16;
      int c4 = (tid & 31) << 2;
      f32x4 v = *(const f32x4*)&ybuf[row][c4];
      __builtin_nontemporal_store(v, (f32x4*)&out[((r0 + row)*T_ + (t-1))*L_ + c4]);
    }
    VMWAIT0;                               // store-acks out of vmcnt

    evalf(d);                              // k1
    #pragma unroll
    for (int p = 0; p < 2; ++p)
      #pragma unroll
      for (int j = 0; j < 4; ++j){
        float k = d[p][j] + b2v;
        yn[p][j] = yr[p][j] + dt*(2.0f/9.0f)*k;
        float xs = yr[p][j] + 0.5f*dt*k;
        int row = p*16 + 4*hi + j;
        *(unsigned short*)((char*)xb + row*XROWB + ((c3*2) ^ ((row & 7) << 4))) = f2bf(xs);
      }

    __syncthreads();
    evalf(d);                              // k2
    #pragma unroll
    for (int p = 0; p < 2; ++p)
      #pragma unroll
      for (int j = 0; j < 4; ++j){
        float k = d[p][j] + b2v;
        yn[p][j] += dt*(1.0f/3.0f)*k;
        float xs = yr[p][j] + 0.75f*dt*k;
        int row = p*16 + 4*hi + j;
        *(unsigned short*)((char*)xb + row*XROWB + ((c3*2) ^ ((row & 7) << 4))) = f2bf(xs);
      }

    __syncthreads();
    evalf(d);                              // k3
    #pragma unroll
    for (int p = 0; p < 2; ++p)
      #pragma unroll
      for (int j = 0; j < 4; ++j){
        float k = d[p][j] + b2v;
        yn[p][j] += dt*(4.0f/9.0f)*k;
        yr[p][j] = yn[p][j];
        int row = p*16 + 4*hi + j;
        ybuf[row][c3] = yr[p][j];
        *(unsigned short*)((char*)xb + row*XROWB + ((c3*2) ^ ((row & 7) << 4))) = f2bf(yr[p][j]);
      }
  }

  // final slice t = T_-1
  __syncthreads();
  #pragma unroll
  for (int it = 0; it < 2; ++it){
    int row = (tid >> 5) + it*16;
    int c4 = (tid & 31) << 2;
    f32x4 v = *(const f32x4*)&ybuf[row][c4];
    __builtin_nontemporal_store(v, (f32x4*)&out[((r0 + row)*T_ + (T_-1))*L_ + c4]);
  }
}

extern "C" void kernel_launch(void* const* d_in, const int* in_sizes, int n_in,
                              void* d_out, int out_size, void* d_ws, size_t ws_size,
                              hipStream_t stream) {
  const float* x0   = (const float*)d_in[0];
  const float* ts   = (const float*)d_in[1];
  const float* args = (const float*)d_in[2];
  const float* W0   = (const float*)d_in[3];
  const float* b0   = (const float*)d_in[4];
  const float* W1   = (const float*)d_in[5];
  const float* b1   = (const float*)d_in[6];
  const float* W2   = (const float*)d_in[7];
  const float* b2   = (const float*)d_in[8];
  unsigned short* wp = (unsigned short*)d_ws;   // 819,200 B weights + 512 B dts
  float* out = (float*)d_out;

  prep_weights<<<(WTOT + T_ + 255)/256, 256, 0, stream>>>(W0, W1, W2, ts, wp);
  ode_main<<<NBLK, 512, 0, stream>>>(x0, args, b0, b1, b2, wp, out);
}